// Round 3
// baseline (878.925 us; speedup 1.0000x reference)
//
#include <hip/hip_runtime.h>
#include <stdint.h>

#define DIMN 1024
#define TSTEPS 2048
#define BATCH 16
#define MTOT (TSTEPS*BATCH)   // 32768
#define CH (BATCH*DIMN)       // 16384 channels

typedef unsigned short u16;
typedef __attribute__((ext_vector_type(8))) __bf16 bf16x8;
typedef __attribute__((ext_vector_type(4))) float floatx4;

__device__ __forceinline__ float bf2f(u16 u) {
    unsigned v = ((unsigned)u) << 16;
    return __builtin_bit_cast(float, v);
}
__device__ __forceinline__ u16 f2bf(float f) {
    __bf16 b = (__bf16)f;   // RNE convert
    return __builtin_bit_cast(u16, b);
}
__device__ __forceinline__ void gl_lds16(const void* g, void* l) {
    __builtin_amdgcn_global_load_lds(
        (const __attribute__((address_space(1))) void*)g,
        (__attribute__((address_space(3))) void*)l,
        16, 0, 0);
}

#define LOG2E  1.4426950408889634f
#define LOG2E2 2.8853900817779268f

// -------- f32 -> bf16 conversion (x and weights) --------
__global__ void cvt_kernel(const float* __restrict__ src, u16* __restrict__ dst, int n4) {
    int i = blockIdx.x * blockDim.x + threadIdx.x;
    if (i >= n4) return;
    float4 v = ((const float4*)src)[i];
    ushort4 o;
    o.x = f2bf(v.x); o.y = f2bf(v.y); o.z = f2bf(v.z); o.w = f2bf(v.w);
    ((ushort4*)dst)[i] = o;
}

// -------- 128x128 MFMA GEMM: C = A(bf16) * W(bf16)^T, 2-phase dbuf pipeline --------
// Flat grid (2048): m_tile = fid>>3, n_tile = fid&7. With round-robin XCD dispatch
// each XCD sees one n_tile only -> its 256KB W panel pins in L2; each A panel is
// consumed by 8 near-simultaneous blocks -> A streams from HBM ~once.
// K-loop: STAGE(next) issued BEFORE compute(cur), vmcnt(0)+barrier AFTER -> the
// 4 staging loads fly under ds_read+MFMA. One barrier per K-step (was two, with
// zero overlap).
__global__ __launch_bounds__(256) void gemm_bt(
    const u16* __restrict__ A, const u16* __restrict__ W,
    const float* __restrict__ bias,
    u16* __restrict__ outB, float* __restrict__ outF,
    const u16* __restrict__ cmp, int mode)
{
    __shared__ alignas(16) u16 a_sh[2][128 * 32];
    __shared__ alignas(16) u16 b_sh[2][128 * 32];
    const int tid  = threadIdx.x;
    const int lane = tid & 63;
    const int wave = tid >> 6;
    const int wm = wave & 1, wn = wave >> 1;
    const int fid = blockIdx.x;
    const int m0 = (fid >> 3) * 128, n0 = (fid & 7) * 128;
    const int row = lane & 15, quad = lane >> 4;

    const u16* Ag0 = A + (size_t)(m0 + (tid >> 2)) * DIMN + (tid & 3) * 8;
    const u16* Ag1 = Ag0 + (size_t)64 * DIMN;
    const u16* Wg0 = W + (size_t)(n0 + (tid >> 2)) * DIMN + (tid & 3) * 8;
    const u16* Wg1 = Wg0 + (size_t)64 * DIMN;

    floatx4 acc[4][4];
    #pragma unroll
    for (int i = 0; i < 4; i++)
        #pragma unroll
        for (int j = 0; j < 4; j++) acc[i][j] = (floatx4)(0.0f);

    int aoff[4], boff[4];
    #pragma unroll
    for (int i = 0; i < 4; i++) aoff[i] = (wm * 64 + i * 16 + row) * 32 + quad * 8;
    #pragma unroll
    for (int j = 0; j < 4; j++) boff[j] = (wn * 64 + j * 16 + row) * 32 + quad * 8;

    // prologue: stage buf0 @ kt=0
    gl_lds16(Ag0, &a_sh[0][tid * 8]);
    gl_lds16(Ag1, &a_sh[0][2048 + tid * 8]);
    gl_lds16(Wg0, &b_sh[0][tid * 8]);
    gl_lds16(Wg1, &b_sh[0][2048 + tid * 8]);
    asm volatile("s_waitcnt vmcnt(0)" ::: "memory");
    __builtin_amdgcn_s_barrier();

    #define COMPUTE(b)                                                             \
    {                                                                              \
        bf16x8 av[4], bv[4];                                                       \
        _Pragma("unroll")                                                          \
        for (int i = 0; i < 4; i++) av[i] = *(const bf16x8*)(&a_sh[b][aoff[i]]);   \
        _Pragma("unroll")                                                          \
        for (int j = 0; j < 4; j++) bv[j] = *(const bf16x8*)(&b_sh[b][boff[j]]);   \
        _Pragma("unroll")                                                          \
        for (int i = 0; i < 4; i++)                                                \
            _Pragma("unroll")                                                      \
            for (int j = 0; j < 4; j++)                                            \
                acc[i][j] = __builtin_amdgcn_mfma_f32_16x16x32_bf16(               \
                    av[i], bv[j], acc[i][j], 0, 0, 0);                             \
    }

    for (int kt = 0; kt < DIMN; kt += 64) {
        // phase A: prefetch buf1 @ kt+32 (always in range), compute buf0 @ kt
        gl_lds16(Ag0 + kt + 32, &a_sh[1][tid * 8]);
        gl_lds16(Ag1 + kt + 32, &a_sh[1][2048 + tid * 8]);
        gl_lds16(Wg0 + kt + 32, &b_sh[1][tid * 8]);
        gl_lds16(Wg1 + kt + 32, &b_sh[1][2048 + tid * 8]);
        COMPUTE(0);
        asm volatile("s_waitcnt vmcnt(0)" ::: "memory");
        __builtin_amdgcn_s_barrier();
        // phase B: prefetch buf0 @ kt+64 (if in range), compute buf1 @ kt+32
        if (kt + 64 < DIMN) {
            gl_lds16(Ag0 + kt + 64, &a_sh[0][tid * 8]);
            gl_lds16(Ag1 + kt + 64, &a_sh[0][2048 + tid * 8]);
            gl_lds16(Wg0 + kt + 64, &b_sh[0][tid * 8]);
            gl_lds16(Wg1 + kt + 64, &b_sh[0][2048 + tid * 8]);
        }
        COMPUTE(1);
        asm volatile("s_waitcnt vmcnt(0)" ::: "memory");
        __builtin_amdgcn_s_barrier();
    }
    #undef COMPUTE

    // C/D mapping: col = lane&15, row = quad*4 + reg
    const int mb = m0 + wm * 64 + quad * 4;
    const int nb = n0 + wn * 64 + row;
    if (mode == 2) {
        #pragma unroll
        for (int i = 0; i < 4; i++)
            #pragma unroll
            for (int j = 0; j < 4; j++)
                #pragma unroll
                for (int r = 0; r < 4; r++) {
                    size_t idx = (size_t)(mb + i * 16 + r) * DIMN + (nb + j * 16);
                    float z = acc[i][j][r];
                    float sil = z * __builtin_amdgcn_rcpf(1.f + __builtin_amdgcn_exp2f(-z * LOG2E));
                    outF[idx] = bf2f(cmp[idx]) * sil;
                }
    } else if (mode == 0) {
        #pragma unroll
        for (int i = 0; i < 4; i++)
            #pragma unroll
            for (int j = 0; j < 4; j++)
                #pragma unroll
                for (int r = 0; r < 4; r++) {
                    int n = nb + j * 16;
                    float v = acc[i][j][r] + bias[n];
                    v = __builtin_amdgcn_rcpf(1.f + __builtin_amdgcn_exp2f(-v * LOG2E));
                    outB[(size_t)(mb + i * 16 + r) * DIMN + n] = f2bf(v);
                }
    } else {
        #pragma unroll
        for (int i = 0; i < 4; i++)
            #pragma unroll
            for (int j = 0; j < 4; j++)
                #pragma unroll
                for (int r = 0; r < 4; r++) {
                    int n = nb + j * 16;
                    float v = acc[i][j][r] + bias[n];
                    outB[(size_t)(mb + i * 16 + r) * DIMN + n] = f2bf(v);
                }
    }
}

// -------- diagonal scan: recurrence + f32 h store only --------
// One wave per block, one channel per lane, 256 blocks = 1 wave/CU.
// Serial chain per step: fma -> exp2 -> add -> rcp -> fma (~28 cy); bf16 cast
// moved to post_kernel (halves per-step vmem ops + vmcnt pollution).
#define CS 64
#define SB 8
__global__ __launch_bounds__(64) void scan_kernel(
    const u16* __restrict__ dB, const u16* __restrict__ cB,
    const float* __restrict__ h0, const float* __restrict__ r_h,
    float* __restrict__ hAll)
{
    __shared__ alignas(16) u16 d_sh[2][CS * 64];
    __shared__ alignas(16) u16 c_sh[2][CS * 64];
    const int tid = threadIdx.x;
    const int c0 = blockIdx.x * 64;
    const int c  = c0 + tid;
    const int d  = c & (DIMN - 1);

    float h = h0[c];
    const float r2 = r_h[d] * LOG2E2;   // fold 2*log2(e) into the per-channel constant
    hAll[c] = h;                        // h_all[0] = h0

    // Per-lane global source for 16B staging loads: step group row = tid>>3, col = (tid&7)*8
    const u16* dG = dB + (size_t)(tid >> 3) * CH + c0 + (tid & 7) * 8;
    const u16* cG = cB + (size_t)(tid >> 3) * CH + c0 + (tid & 7) * 8;

    // Prologue: stage chunk 0 into buffer 0 (16 loads)
    #pragma unroll
    for (int s = 0; s < 8; s++) {
        gl_lds16(dG + (size_t)(s * 8) * CH, (void*)&d_sh[0][s * 512]);
        gl_lds16(cG + (size_t)(s * 8) * CH, (void*)&c_sh[0][s * 512]);
    }

    float* hOut = hAll + CH + c;   // h_{t+1} stream (f32, required output)

    for (int t0 = 0; t0 < TSTEPS; t0 += CS) {
        const int buf = (t0 / CS) & 1;
        if (t0 + CS < TSTEPS) {
            // issue next chunk's 16 staging loads, then wait only for the CURRENT
            // chunk (everything older than the 16 just issued)
            #pragma unroll
            for (int s = 0; s < 8; s++) {
                gl_lds16(dG + (size_t)(t0 + CS + s * 8) * CH, (void*)&d_sh[buf ^ 1][s * 512]);
                gl_lds16(cG + (size_t)(t0 + CS + s * 8) * CH, (void*)&c_sh[buf ^ 1][s * 512]);
            }
            asm volatile("s_waitcnt vmcnt(16)" ::: "memory");
        } else {
            asm volatile("s_waitcnt vmcnt(0)" ::: "memory");
        }
        __builtin_amdgcn_sched_barrier(0);

        const u16* dS = d_sh[buf];
        const u16* cS = c_sh[buf];

        #pragma unroll
        for (int sb = 0; sb < CS / SB; sb++) {
            #pragma unroll
            for (int i = 0; i < SB; i++) {
                const int s = sb * SB + i;
                float dlt  = bf2f(dS[s * 64 + tid]);
                float cin2 = bf2f(cS[s * 64 + tid]) * LOG2E2;   // off-chain
                // critical chain: fma -> exp2 -> add -> rcp -> fma
                float e    = __builtin_amdgcn_exp2f(fmaf(r2, h, cin2));
                float q    = __builtin_amdgcn_rcpf(e + 1.f);
                // off-chain (parallel with exp2/rcp): base = h - dlt*h + dlt, m2d = -2*dlt
                float base = fmaf(-dlt, h, h) + dlt;
                float m2d  = -2.f * dlt;
                h = fmaf(m2d, q, base);   // == (1-dlt)*h + dlt*tanh(...)
                hOut[(size_t)(t0 + s) * CH] = h;
            }
        }
    }
}

// -------- parallel group-softmax + bf16 cast of h (post-scan, BW-bound) --------
// one thread = 4 channels (float4); 8 threads = one 32-wide softmax group.
// |h| < 1 by induction (h0=0, convex comb. with tanh) => no max subtraction needed.
__global__ __launch_bounds__(256) void post_kernel(
    const float* __restrict__ hAll, u16* __restrict__ hB, u16* __restrict__ cmp)
{
    const int gid = blockIdx.x * 256 + threadIdx.x;     // over T*CH/4
    float4 hv = ((const float4*)(hAll + CH))[gid];

    float ex = __builtin_amdgcn_exp2f(hv.x * LOG2E);
    float ey = __builtin_amdgcn_exp2f(hv.y * LOG2E);
    float ez = __builtin_amdgcn_exp2f(hv.z * LOG2E);
    float ew = __builtin_amdgcn_exp2f(hv.w * LOG2E);
    float sum = (ex + ey) + (ez + ew);
    #pragma unroll
    for (int s = 4; s > 0; s >>= 1) sum += __shfl_xor(sum, s);  // 8-thread group = 32 ch
    float inv = __builtin_amdgcn_rcpf(sum);

    ushort4 co, ho;
    co.x = f2bf(ex * inv); co.y = f2bf(ey * inv);
    co.z = f2bf(ez * inv); co.w = f2bf(ew * inv);
    ho.x = f2bf(hv.x); ho.y = f2bf(hv.y); ho.z = f2bf(hv.z); ho.w = f2bf(hv.w);
    ((ushort4*)cmp)[gid] = co;
    ((ushort4*)hB)[gid] = ho;
}

extern "C" void kernel_launch(void* const* d_in, const int* in_sizes, int n_in,
                              void* d_out, int out_size, void* d_ws, size_t ws_size,
                              hipStream_t stream) {
    const float* x   = (const float*)d_in[0];
    const float* h0  = (const float*)d_in[1];
    const float* W_x = (const float*)d_in[2];
    const float* r_h = (const float*)d_in[3];
    const float* b   = (const float*)d_in[4];
    const float* W_d = (const float*)d_in[5];
    const float* b_d = (const float*)d_in[6];
    const float* W_o = (const float*)d_in[7];
    float* out = (float*)d_out;

    char* ws = (char*)d_ws;
    u16* xb   = (u16*)(ws);
    u16* wdB  = (u16*)(ws + 67108864);
    u16* wxB  = (u16*)(ws + 69206016);
    u16* woB  = (u16*)(ws + 71303168);
    u16* dBuf = (u16*)(ws + 73400320);
    u16* cBuf = (u16*)(ws + 140509184);
    u16* cmpB = (u16*)(ws + 207618048);
    u16* hB   = xb;   // xb dead after the two pre-GEMMs

    cvt_kernel<<<dim3(33554432 / 4 / 256), 256, 0, stream>>>(x, xb, 33554432 / 4);
    cvt_kernel<<<dim3(1048576 / 4 / 256), 256, 0, stream>>>(W_d, wdB, 1048576 / 4);
    cvt_kernel<<<dim3(1048576 / 4 / 256), 256, 0, stream>>>(W_x, wxB, 1048576 / 4);
    cvt_kernel<<<dim3(1048576 / 4 / 256), 256, 0, stream>>>(W_o, woB, 1048576 / 4);

    dim3 g(MTOT / 128 * (DIMN / 128));   // 2048 flat
    gemm_bt<<<g, 256, 0, stream>>>(xb, wdB, b_d, dBuf, nullptr, nullptr, 0);
    gemm_bt<<<g, 256, 0, stream>>>(xb, wxB, b,   cBuf, nullptr, nullptr, 1);
    scan_kernel<<<256, 64, 0, stream>>>(dBuf, cBuf, h0, r_h, out);
    post_kernel<<<dim3(TSTEPS * CH / 4 / 256), 256, 0, stream>>>(out, hB, cmpB);
    gemm_bt<<<g, 256, 0, stream>>>(hB, woB, nullptr, nullptr, out + 33570816, cmpB, 2);
}

// Round 4
// 808.674 us; speedup vs baseline: 1.0869x; 1.0869x over previous
//
#include <hip/hip_runtime.h>
#include <stdint.h>

#define DIMN 1024
#define TSTEPS 2048
#define BATCH 16
#define MTOT (TSTEPS*BATCH)   // 32768
#define CH (BATCH*DIMN)       // 16384 channels

typedef unsigned short u16;
typedef __attribute__((ext_vector_type(8))) __bf16 bf16x8;
typedef __attribute__((ext_vector_type(4))) float floatx4;

__device__ __forceinline__ float bf2f(u16 u) {
    unsigned v = ((unsigned)u) << 16;
    return __builtin_bit_cast(float, v);
}
__device__ __forceinline__ u16 f2bf(float f) {
    __bf16 b = (__bf16)f;   // RNE convert
    return __builtin_bit_cast(u16, b);
}
__device__ __forceinline__ void gl_lds16(const void* g, void* l) {
    __builtin_amdgcn_global_load_lds(
        (const __attribute__((address_space(1))) void*)g,
        (__attribute__((address_space(3))) void*)l,
        16, 0, 0);
}

#define LOG2E  1.4426950408889634f
#define LOG2E2 2.8853900817779268f

// -------- f32 -> bf16 conversion (x and weights) --------
__global__ void cvt_kernel(const float* __restrict__ src, u16* __restrict__ dst, int n4) {
    int i = blockIdx.x * blockDim.x + threadIdx.x;
    if (i >= n4) return;
    float4 v = ((const float4*)src)[i];
    ushort4 o;
    o.x = f2bf(v.x); o.y = f2bf(v.y); o.z = f2bf(v.z); o.w = f2bf(v.w);
    ((ushort4*)dst)[i] = o;
}

// -------- 128x128 MFMA GEMM: C = A(bf16) * W(bf16)^T ------------------------
// 4-buffer, 2-ahead, counted-vmcnt pipeline (T4): per phase issue STAGE(t+2),
// wait vmcnt(8) (= 8 loads of t+1/t+2 in flight => stage(t) landed), one raw
// s_barrier, compute. No vmcnt(0) drain in steady state -> staging latency is
// hidden across 2 full phases. WAR safe: stage(t+2) overwrites the buffer last
// read by compute(t-2), two barriers apart. Fully unrolled (K=1024, 32 steps).
// Grid m-fastest: m-tile = fid&255 -> XCD = m&7 (A panel L2-affine across the
// 8 n-epochs), n-tile = fid>>8.
__global__ __launch_bounds__(256) void gemm_bt(
    const u16* __restrict__ A, const u16* __restrict__ W,
    const float* __restrict__ bias,
    u16* __restrict__ outB, float* __restrict__ outF,
    const u16* __restrict__ cmp, int mode)
{
    __shared__ alignas(16) u16 a_sh[4][128 * 32];
    __shared__ alignas(16) u16 b_sh[4][128 * 32];
    const int tid  = threadIdx.x;
    const int lane = tid & 63;
    const int wave = tid >> 6;
    const int wm = wave & 1, wn = wave >> 1;
    const int fid = blockIdx.x;
    const int m0 = (fid & 255) * 128, n0 = (fid >> 8) * 128;
    const int row = lane & 15, quad = lane >> 4;

    const u16* Ag0 = A + (size_t)(m0 + (tid >> 2)) * DIMN + (tid & 3) * 8;
    const u16* Ag1 = Ag0 + (size_t)64 * DIMN;
    const u16* Wg0 = W + (size_t)(n0 + (tid >> 2)) * DIMN + (tid & 3) * 8;
    const u16* Wg1 = Wg0 + (size_t)64 * DIMN;

    floatx4 acc[4][4];
    #pragma unroll
    for (int i = 0; i < 4; i++)
        #pragma unroll
        for (int j = 0; j < 4; j++) acc[i][j] = (floatx4)(0.0f);

    int aoff[4], boff[4];
    #pragma unroll
    for (int i = 0; i < 4; i++) aoff[i] = (wm * 64 + i * 16 + row) * 32 + quad * 8;
    #pragma unroll
    for (int j = 0; j < 4; j++) boff[j] = (wn * 64 + j * 16 + row) * 32 + quad * 8;

    #define STAGE(t_) {                                                        \
        const int pb_ = (t_) & 3; const int kp_ = (t_) * 32;                   \
        gl_lds16(Ag0 + kp_, &a_sh[pb_][tid * 8]);                              \
        gl_lds16(Ag1 + kp_, &a_sh[pb_][2048 + tid * 8]);                       \
        gl_lds16(Wg0 + kp_, &b_sh[pb_][tid * 8]);                              \
        gl_lds16(Wg1 + kp_, &b_sh[pb_][2048 + tid * 8]);                       \
    }

    STAGE(0);
    STAGE(1);

    #pragma unroll
    for (int t = 0; t < 32; t++) {
        if (t + 2 < 32) STAGE(t + 2);
        if (t < 30)        { asm volatile("s_waitcnt vmcnt(8)" ::: "memory"); }
        else if (t == 30)  { asm volatile("s_waitcnt vmcnt(4)" ::: "memory"); }
        else               { asm volatile("s_waitcnt vmcnt(0)" ::: "memory"); }
        __builtin_amdgcn_sched_barrier(0);
        __builtin_amdgcn_s_barrier();
        const int buf = t & 3;
        bf16x8 av[4], bv[4];
        #pragma unroll
        for (int i = 0; i < 4; i++) av[i] = *(const bf16x8*)(&a_sh[buf][aoff[i]]);
        #pragma unroll
        for (int j = 0; j < 4; j++) bv[j] = *(const bf16x8*)(&b_sh[buf][boff[j]]);
        #pragma unroll
        for (int i = 0; i < 4; i++)
            #pragma unroll
            for (int j = 0; j < 4; j++)
                acc[i][j] = __builtin_amdgcn_mfma_f32_16x16x32_bf16(
                    av[i], bv[j], acc[i][j], 0, 0, 0);
    }
    #undef STAGE

    // C/D mapping: col = lane&15, row = quad*4 + reg
    const int mb = m0 + wm * 64 + quad * 4;
    const int nb = n0 + wn * 64 + row;
    if (mode == 2) {
        #pragma unroll
        for (int i = 0; i < 4; i++)
            #pragma unroll
            for (int j = 0; j < 4; j++)
                #pragma unroll
                for (int r = 0; r < 4; r++) {
                    size_t idx = (size_t)(mb + i * 16 + r) * DIMN + (nb + j * 16);
                    float z = acc[i][j][r];
                    float sil = z * __builtin_amdgcn_rcpf(1.f + __builtin_amdgcn_exp2f(-z * LOG2E));
                    outF[idx] = bf2f(cmp[idx]) * sil;
                }
    } else if (mode == 0) {
        #pragma unroll
        for (int i = 0; i < 4; i++)
            #pragma unroll
            for (int j = 0; j < 4; j++)
                #pragma unroll
                for (int r = 0; r < 4; r++) {
                    int n = nb + j * 16;
                    float v = acc[i][j][r] + bias[n];
                    v = __builtin_amdgcn_rcpf(1.f + __builtin_amdgcn_exp2f(-v * LOG2E));
                    outB[(size_t)(mb + i * 16 + r) * DIMN + n] = f2bf(v);
                }
    } else {
        #pragma unroll
        for (int i = 0; i < 4; i++)
            #pragma unroll
            for (int j = 0; j < 4; j++)
                #pragma unroll
                for (int r = 0; r < 4; r++) {
                    int n = nb + j * 16;
                    float v = acc[i][j][r] + bias[n];
                    outB[(size_t)(mb + i * 16 + r) * DIMN + n] = f2bf(v);
                }
    }
}

// -------- diagonal scan: recurrence + f32 h store only --------
// One wave per block, one channel per lane, 256 blocks = 1 wave/CU.
// Serial chain per step: fma -> exp2 -> add -> rcp -> fma (~28 cy).
// Chunk wait: vmcnt(63) instead of vmcnt(16) -- the old wait force-drained the
// previous chunk's 64 h-stores (older in the in-order vmcnt queue). Since the
// window since the current chunk's 16 loads is 16+64+16 = 96 ops, outstanding
// <= 63 guarantees (in-order retirement) those 16 loads completed, without
// waiting for most stores. Chunk 0 (no stores yet) uses the exact vmcnt(16).
#define CS 64
#define SB 8
__global__ __launch_bounds__(64) void scan_kernel(
    const u16* __restrict__ dB, const u16* __restrict__ cB,
    const float* __restrict__ h0, const float* __restrict__ r_h,
    float* __restrict__ hAll)
{
    __shared__ alignas(16) u16 d_sh[2][CS * 64];
    __shared__ alignas(16) u16 c_sh[2][CS * 64];
    const int tid = threadIdx.x;
    const int c0 = blockIdx.x * 64;
    const int c  = c0 + tid;
    const int d  = c & (DIMN - 1);

    float h = h0[c];
    const float r2 = r_h[d] * LOG2E2;   // fold 2*log2(e) into the per-channel constant
    hAll[c] = h;                        // h_all[0] = h0

    // Per-lane global source for 16B staging loads: step group row = tid>>3, col = (tid&7)*8
    const u16* dG = dB + (size_t)(tid >> 3) * CH + c0 + (tid & 7) * 8;
    const u16* cG = cB + (size_t)(tid >> 3) * CH + c0 + (tid & 7) * 8;

    // Prologue: stage chunk 0 into buffer 0 (16 loads)
    #pragma unroll
    for (int s = 0; s < 8; s++) {
        gl_lds16(dG + (size_t)(s * 8) * CH, (void*)&d_sh[0][s * 512]);
        gl_lds16(cG + (size_t)(s * 8) * CH, (void*)&c_sh[0][s * 512]);
    }

    float* hOut = hAll + CH + c;   // h_{t+1} stream (f32, required output)

    for (int t0 = 0; t0 < TSTEPS; t0 += CS) {
        const int buf = (t0 / CS) & 1;
        if (t0 + CS < TSTEPS) {
            #pragma unroll
            for (int s = 0; s < 8; s++) {
                gl_lds16(dG + (size_t)(t0 + CS + s * 8) * CH, (void*)&d_sh[buf ^ 1][s * 512]);
                gl_lds16(cG + (size_t)(t0 + CS + s * 8) * CH, (void*)&c_sh[buf ^ 1][s * 512]);
            }
        }
        if (t0 == 0) { asm volatile("s_waitcnt vmcnt(16)" ::: "memory"); }
        else         { asm volatile("s_waitcnt vmcnt(63)" ::: "memory"); }
        __builtin_amdgcn_sched_barrier(0);

        const u16* dS = d_sh[buf];
        const u16* cS = c_sh[buf];

        #pragma unroll
        for (int sb = 0; sb < CS / SB; sb++) {
            #pragma unroll
            for (int i = 0; i < SB; i++) {
                const int s = sb * SB + i;
                float dlt  = bf2f(dS[s * 64 + tid]);
                float cin2 = bf2f(cS[s * 64 + tid]) * LOG2E2;   // off-chain
                // critical chain: fma -> exp2 -> add -> rcp -> fma
                float e    = __builtin_amdgcn_exp2f(fmaf(r2, h, cin2));
                float q    = __builtin_amdgcn_rcpf(e + 1.f);
                // off-chain (parallel with exp2/rcp): base = h - dlt*h + dlt, m2d = -2*dlt
                float base = fmaf(-dlt, h, h) + dlt;
                float m2d  = -2.f * dlt;
                h = fmaf(m2d, q, base);   // == (1-dlt)*h + dlt*tanh(...)
                hOut[(size_t)(t0 + s) * CH] = h;
            }
        }
    }
}

// -------- parallel group-softmax + bf16 cast of h (post-scan, BW-bound) --------
// one thread = 4 channels (float4); 8 threads = one 32-wide softmax group.
// |h| < 1 by induction (h0=0, convex comb. with tanh) => no max subtraction needed.
__global__ __launch_bounds__(256) void post_kernel(
    const float* __restrict__ hAll, u16* __restrict__ hB, u16* __restrict__ cmp)
{
    const int gid = blockIdx.x * 256 + threadIdx.x;     // over T*CH/4
    float4 hv = ((const float4*)(hAll + CH))[gid];

    float ex = __builtin_amdgcn_exp2f(hv.x * LOG2E);
    float ey = __builtin_amdgcn_exp2f(hv.y * LOG2E);
    float ez = __builtin_amdgcn_exp2f(hv.z * LOG2E);
    float ew = __builtin_amdgcn_exp2f(hv.w * LOG2E);
    float sum = (ex + ey) + (ez + ew);
    #pragma unroll
    for (int s = 4; s > 0; s >>= 1) sum += __shfl_xor(sum, s);  // 8-thread group = 32 ch
    float inv = __builtin_amdgcn_rcpf(sum);

    ushort4 co, ho;
    co.x = f2bf(ex * inv); co.y = f2bf(ey * inv);
    co.z = f2bf(ez * inv); co.w = f2bf(ew * inv);
    ho.x = f2bf(hv.x); ho.y = f2bf(hv.y); ho.z = f2bf(hv.z); ho.w = f2bf(hv.w);
    ((ushort4*)cmp)[gid] = co;
    ((ushort4*)hB)[gid] = ho;
}

extern "C" void kernel_launch(void* const* d_in, const int* in_sizes, int n_in,
                              void* d_out, int out_size, void* d_ws, size_t ws_size,
                              hipStream_t stream) {
    const float* x   = (const float*)d_in[0];
    const float* h0  = (const float*)d_in[1];
    const float* W_x = (const float*)d_in[2];
    const float* r_h = (const float*)d_in[3];
    const float* b   = (const float*)d_in[4];
    const float* W_d = (const float*)d_in[5];
    const float* b_d = (const float*)d_in[6];
    const float* W_o = (const float*)d_in[7];
    float* out = (float*)d_out;

    char* ws = (char*)d_ws;
    u16* xb   = (u16*)(ws);
    u16* wdB  = (u16*)(ws + 67108864);
    u16* wxB  = (u16*)(ws + 69206016);
    u16* woB  = (u16*)(ws + 71303168);
    u16* dBuf = (u16*)(ws + 73400320);
    u16* cBuf = (u16*)(ws + 140509184);
    u16* cmpB = (u16*)(ws + 207618048);
    u16* hB   = xb;   // xb dead after the two pre-GEMMs

    cvt_kernel<<<dim3(33554432 / 4 / 256), 256, 0, stream>>>(x, xb, 33554432 / 4);
    cvt_kernel<<<dim3(1048576 / 4 / 256), 256, 0, stream>>>(W_d, wdB, 1048576 / 4);
    cvt_kernel<<<dim3(1048576 / 4 / 256), 256, 0, stream>>>(W_x, wxB, 1048576 / 4);
    cvt_kernel<<<dim3(1048576 / 4 / 256), 256, 0, stream>>>(W_o, woB, 1048576 / 4);

    dim3 g(MTOT / 128 * (DIMN / 128));   // 2048 flat, m-fastest
    gemm_bt<<<g, 256, 0, stream>>>(xb, wdB, b_d, dBuf, nullptr, nullptr, 0);
    gemm_bt<<<g, 256, 0, stream>>>(xb, wxB, b,   cBuf, nullptr, nullptr, 1);
    scan_kernel<<<256, 64, 0, stream>>>(dBuf, cBuf, h0, r_h, out);
    post_kernel<<<dim3(TSTEPS * CH / 4 / 256), 256, 0, stream>>>(out, hB, cmpB);
    gemm_bt<<<g, 256, 0, stream>>>(hB, woB, nullptr, nullptr, out + 33570816, cmpB, 2);
}

// Round 5
// 780.833 us; speedup vs baseline: 1.1256x; 1.0357x over previous
//
#include <hip/hip_runtime.h>
#include <stdint.h>

#define DIMN 1024
#define TSTEPS 2048
#define BATCH 16
#define MTOT (TSTEPS*BATCH)   // 32768
#define CH (BATCH*DIMN)       // 16384 channels

typedef unsigned short u16;
typedef __attribute__((ext_vector_type(8))) __bf16 bf16x8;
typedef __attribute__((ext_vector_type(4))) float floatx4;

__device__ __forceinline__ float bf2f(u16 u) {
    unsigned v = ((unsigned)u) << 16;
    return __builtin_bit_cast(float, v);
}
__device__ __forceinline__ u16 f2bf(float f) {
    __bf16 b = (__bf16)f;   // RNE convert
    return __builtin_bit_cast(u16, b);
}
__device__ __forceinline__ void gl_lds16(const void* g, void* l) {
    __builtin_amdgcn_global_load_lds(
        (const __attribute__((address_space(1))) void*)g,
        (__attribute__((address_space(3))) void*)l,
        16, 0, 0);
}

#define LOG2E  1.4426950408889634f
#define LOG2E2 2.8853900817779268f

// -------- f32 -> bf16 conversion (x and weights) --------
__global__ void cvt_kernel(const float* __restrict__ src, u16* __restrict__ dst, int n4) {
    int i = blockIdx.x * blockDim.x + threadIdx.x;
    if (i >= n4) return;
    float4 v = ((const float4*)src)[i];
    ushort4 o;
    o.x = f2bf(v.x); o.y = f2bf(v.y); o.z = f2bf(v.z); o.w = f2bf(v.w);
    ((ushort4*)dst)[i] = o;
}

// -------- 256x256 MFMA GEMM: C = A(bf16) * W(bf16)^T ------------------------
// 8 waves (512 thr), per-wave output 128x64 (WM=2 x WN=4). BK=64, 2 LDS bufs
// (128 KiB), stage-early / drain-late 2-phase: STAGE(t+1) issued BEFORE the
// ~2500-cy compute of tile t, vmcnt(0)+barrier AFTER -> drain is free.
// T2 swizzle (both-sides, LDS stays linear per G21): chunk-in-row ^= row&7
// (byte ^ ((row&7)<<4), 128B rows) applied to the GLOBAL source of
// global_load_lds and identically to the ds_read address. 16-lane column
// reads then spread across all 8 16B slots -> 2 lanes/bank = conflict-free.
// Grid m-fastest: m-tile = fid&127 (XCD affinity), n-tile = fid>>7.
__global__ __launch_bounds__(512, 2) void gemm_bt(
    const u16* __restrict__ A, const u16* __restrict__ W,
    const float* __restrict__ bias,
    u16* __restrict__ outB, float* __restrict__ outF,
    const u16* __restrict__ cmp, int mode)
{
    __shared__ alignas(16) u16 a_sh[2][256 * 64];
    __shared__ alignas(16) u16 b_sh[2][256 * 64];
    const int tid  = threadIdx.x;
    const int lane = tid & 63;
    const int wid  = tid >> 6;
    const int wm = wid >> 2, wn = wid & 3;     // 2 x 4 wave grid
    const int fid = blockIdx.x;
    const int m0 = (fid & 127) * 256, n0 = (fid >> 7) * 256;
    const int row16 = lane & 15, quad = lane >> 4;
    const int xm = (row16 & 7) << 4;           // read-side swizzle XOR (bytes)

    // Staging: per buf, A tile = 256 rows x 64 cols bf16 = 32 KB = 512 thr x 4
    // chunks of 16B. Linear LDS dest chunk q = l*512+tid; global source column
    // pre-swizzled: chunk-in-row = (q&7) ^ (row&7).
    const u16* aSrc[4]; const u16* wSrc[4]; int dQ[4];
    #pragma unroll
    for (int l = 0; l < 4; l++) {
        const int q = l * 512 + tid;
        const int r = q >> 3;
        const int cs = ((q & 7) ^ (r & 7)) * 8;
        dQ[l] = q * 8;
        aSrc[l] = A + (size_t)(m0 + r) * DIMN + cs;
        wSrc[l] = W + (size_t)(n0 + r) * DIMN + cs;
    }

    floatx4 acc[8][4];
    #pragma unroll
    for (int i = 0; i < 8; i++)
        #pragma unroll
        for (int j = 0; j < 4; j++) acc[i][j] = (floatx4)(0.0f);

    #define STAGE(t_) {                                                        \
        const int pb_ = (t_) & 1; const int kp_ = (t_) * 64;                   \
        _Pragma("unroll")                                                      \
        for (int l = 0; l < 4; l++) {                                          \
            gl_lds16(aSrc[l] + kp_, &a_sh[pb_][dQ[l]]);                        \
            gl_lds16(wSrc[l] + kp_, &b_sh[pb_][dQ[l]]);                        \
        }                                                                      \
    }

    STAGE(0);
    asm volatile("s_waitcnt vmcnt(0)" ::: "memory");
    __builtin_amdgcn_sched_barrier(0);
    __builtin_amdgcn_s_barrier();
    __builtin_amdgcn_sched_barrier(0);

    #pragma unroll
    for (int t = 0; t < 16; t++) {
        if (t < 15) STAGE(t + 1);
        const char* ab = (const char*)a_sh[t & 1];
        const char* bb = (const char*)b_sh[t & 1];
        #pragma unroll
        for (int ks = 0; ks < 2; ks++) {
            bf16x8 av[8], bv[4];
            #pragma unroll
            for (int i = 0; i < 8; i++)
                av[i] = *(const bf16x8*)(ab +
                    (((wm * 128 + i * 16 + row16) * 128 + ks * 64 + quad * 16) ^ xm));
            #pragma unroll
            for (int j = 0; j < 4; j++)
                bv[j] = *(const bf16x8*)(bb +
                    (((wn * 64 + j * 16 + row16) * 128 + ks * 64 + quad * 16) ^ xm));
            #pragma unroll
            for (int i = 0; i < 8; i++)
                #pragma unroll
                for (int j = 0; j < 4; j++)
                    acc[i][j] = __builtin_amdgcn_mfma_f32_16x16x32_bf16(
                        av[i], bv[j], acc[i][j], 0, 0, 0);
        }
        asm volatile("s_waitcnt vmcnt(0)" ::: "memory");
        __builtin_amdgcn_sched_barrier(0);
        __builtin_amdgcn_s_barrier();
        __builtin_amdgcn_sched_barrier(0);
    }
    #undef STAGE

    // C/D mapping: col = lane&15, row = quad*4 + reg
    const int mb = m0 + wm * 128 + quad * 4;
    const int nb = n0 + wn * 64 + row16;
    if (mode == 2) {
        #pragma unroll
        for (int i = 0; i < 8; i++)
            #pragma unroll
            for (int j = 0; j < 4; j++)
                #pragma unroll
                for (int r = 0; r < 4; r++) {
                    size_t idx = (size_t)(mb + i * 16 + r) * DIMN + (nb + j * 16);
                    float z = acc[i][j][r];
                    float sil = z * __builtin_amdgcn_rcpf(1.f + __builtin_amdgcn_exp2f(-z * LOG2E));
                    outF[idx] = bf2f(cmp[idx]) * sil;
                }
    } else if (mode == 0) {
        #pragma unroll
        for (int i = 0; i < 8; i++)
            #pragma unroll
            for (int j = 0; j < 4; j++)
                #pragma unroll
                for (int r = 0; r < 4; r++) {
                    int n = nb + j * 16;
                    float v = acc[i][j][r] + bias[n];
                    v = __builtin_amdgcn_rcpf(1.f + __builtin_amdgcn_exp2f(-v * LOG2E));
                    outB[(size_t)(mb + i * 16 + r) * DIMN + n] = f2bf(v);
                }
    } else {
        #pragma unroll
        for (int i = 0; i < 8; i++)
            #pragma unroll
            for (int j = 0; j < 4; j++)
                #pragma unroll
                for (int r = 0; r < 4; r++) {
                    int n = nb + j * 16;
                    float v = acc[i][j][r] + bias[n];
                    outB[(size_t)(mb + i * 16 + r) * DIMN + n] = f2bf(v);
                }
    }
}

// -------- diagonal scan: recurrence + f32 h store only --------
// One wave per block, one channel per lane, 256 blocks = 1 wave/CU.
// Serial chain per step: fma -> exp2 -> add -> rcp -> fma (~28 cy).
// Chunk wait: vmcnt(63) (in-order retirement over the 96-op window guarantees
// the current chunk's 16 loads completed without draining prior h-stores);
// chunk 0 uses the exact vmcnt(16).
#define CS 64
#define SB 8
__global__ __launch_bounds__(64) void scan_kernel(
    const u16* __restrict__ dB, const u16* __restrict__ cB,
    const float* __restrict__ h0, const float* __restrict__ r_h,
    float* __restrict__ hAll)
{
    __shared__ alignas(16) u16 d_sh[2][CS * 64];
    __shared__ alignas(16) u16 c_sh[2][CS * 64];
    const int tid = threadIdx.x;
    const int c0 = blockIdx.x * 64;
    const int c  = c0 + tid;
    const int d  = c & (DIMN - 1);

    float h = h0[c];
    const float r2 = r_h[d] * LOG2E2;   // fold 2*log2(e) into the per-channel constant
    hAll[c] = h;                        // h_all[0] = h0

    const u16* dG = dB + (size_t)(tid >> 3) * CH + c0 + (tid & 7) * 8;
    const u16* cG = cB + (size_t)(tid >> 3) * CH + c0 + (tid & 7) * 8;

    #pragma unroll
    for (int s = 0; s < 8; s++) {
        gl_lds16(dG + (size_t)(s * 8) * CH, (void*)&d_sh[0][s * 512]);
        gl_lds16(cG + (size_t)(s * 8) * CH, (void*)&c_sh[0][s * 512]);
    }

    float* hOut = hAll + CH + c;   // h_{t+1} stream (f32, required output)

    for (int t0 = 0; t0 < TSTEPS; t0 += CS) {
        const int buf = (t0 / CS) & 1;
        if (t0 + CS < TSTEPS) {
            #pragma unroll
            for (int s = 0; s < 8; s++) {
                gl_lds16(dG + (size_t)(t0 + CS + s * 8) * CH, (void*)&d_sh[buf ^ 1][s * 512]);
                gl_lds16(cG + (size_t)(t0 + CS + s * 8) * CH, (void*)&c_sh[buf ^ 1][s * 512]);
            }
        }
        if (t0 == 0) { asm volatile("s_waitcnt vmcnt(16)" ::: "memory"); }
        else         { asm volatile("s_waitcnt vmcnt(63)" ::: "memory"); }
        __builtin_amdgcn_sched_barrier(0);

        const u16* dS = d_sh[buf];
        const u16* cS = c_sh[buf];

        #pragma unroll
        for (int sb = 0; sb < CS / SB; sb++) {
            #pragma unroll
            for (int i = 0; i < SB; i++) {
                const int s = sb * SB + i;
                float dlt  = bf2f(dS[s * 64 + tid]);
                float cin2 = bf2f(cS[s * 64 + tid]) * LOG2E2;   // off-chain
                // critical chain: fma -> exp2 -> add -> rcp -> fma
                float e    = __builtin_amdgcn_exp2f(fmaf(r2, h, cin2));
                float q    = __builtin_amdgcn_rcpf(e + 1.f);
                float base = fmaf(-dlt, h, h) + dlt;
                float m2d  = -2.f * dlt;
                h = fmaf(m2d, q, base);   // == (1-dlt)*h + dlt*tanh(...)
                hOut[(size_t)(t0 + s) * CH] = h;
            }
        }
    }
}

// -------- parallel group-softmax + bf16 cast of h (post-scan, BW-bound) --------
__global__ __launch_bounds__(256) void post_kernel(
    const float* __restrict__ hAll, u16* __restrict__ hB, u16* __restrict__ cmp)
{
    const int gid = blockIdx.x * 256 + threadIdx.x;     // over T*CH/4
    float4 hv = ((const float4*)(hAll + CH))[gid];

    float ex = __builtin_amdgcn_exp2f(hv.x * LOG2E);
    float ey = __builtin_amdgcn_exp2f(hv.y * LOG2E);
    float ez = __builtin_amdgcn_exp2f(hv.z * LOG2E);
    float ew = __builtin_amdgcn_exp2f(hv.w * LOG2E);
    float sum = (ex + ey) + (ez + ew);
    #pragma unroll
    for (int s = 4; s > 0; s >>= 1) sum += __shfl_xor(sum, s);  // 8-thread group = 32 ch
    float inv = __builtin_amdgcn_rcpf(sum);

    ushort4 co, ho;
    co.x = f2bf(ex * inv); co.y = f2bf(ey * inv);
    co.z = f2bf(ez * inv); co.w = f2bf(ew * inv);
    ho.x = f2bf(hv.x); ho.y = f2bf(hv.y); ho.z = f2bf(hv.z); ho.w = f2bf(hv.w);
    ((ushort4*)cmp)[gid] = co;
    ((ushort4*)hB)[gid] = ho;
}

extern "C" void kernel_launch(void* const* d_in, const int* in_sizes, int n_in,
                              void* d_out, int out_size, void* d_ws, size_t ws_size,
                              hipStream_t stream) {
    const float* x   = (const float*)d_in[0];
    const float* h0  = (const float*)d_in[1];
    const float* W_x = (const float*)d_in[2];
    const float* r_h = (const float*)d_in[3];
    const float* b   = (const float*)d_in[4];
    const float* W_d = (const float*)d_in[5];
    const float* b_d = (const float*)d_in[6];
    const float* W_o = (const float*)d_in[7];
    float* out = (float*)d_out;

    char* ws = (char*)d_ws;
    u16* xb   = (u16*)(ws);
    u16* wdB  = (u16*)(ws + 67108864);
    u16* wxB  = (u16*)(ws + 69206016);
    u16* woB  = (u16*)(ws + 71303168);
    u16* dBuf = (u16*)(ws + 73400320);
    u16* cBuf = (u16*)(ws + 140509184);
    u16* cmpB = (u16*)(ws + 207618048);
    u16* hB   = xb;   // xb dead after the two pre-GEMMs

    cvt_kernel<<<dim3(33554432 / 4 / 256), 256, 0, stream>>>(x, xb, 33554432 / 4);
    cvt_kernel<<<dim3(1048576 / 4 / 256), 256, 0, stream>>>(W_d, wdB, 1048576 / 4);
    cvt_kernel<<<dim3(1048576 / 4 / 256), 256, 0, stream>>>(W_x, wxB, 1048576 / 4);
    cvt_kernel<<<dim3(1048576 / 4 / 256), 256, 0, stream>>>(W_o, woB, 1048576 / 4);

    dim3 g(MTOT / 256 * (DIMN / 256));   // 512 flat, m-fastest
    gemm_bt<<<g, 512, 0, stream>>>(xb, wdB, b_d, dBuf, nullptr, nullptr, 0);
    gemm_bt<<<g, 512, 0, stream>>>(xb, wxB, b,   cBuf, nullptr, nullptr, 1);
    scan_kernel<<<256, 64, 0, stream>>>(dBuf, cBuf, h0, r_h, out);
    post_kernel<<<dim3(TSTEPS * CH / 4 / 256), 256, 0, stream>>>(out, hB, cmpB);
    gemm_bt<<<g, 512, 0, stream>>>(hB, woB, nullptr, nullptr, out + 33570816, cmpB, 2);
}